// Round 8
// baseline (100.527 us; speedup 1.0000x reference)
//
#include <hip/hip_runtime.h>
#include <cstddef>

#define CCH 256
#define NPIX 4096
#define NB 8
#define INVCNT (1.0f/32768.0f)
#define INVN (1.0f/4096.0f)

typedef __bf16 bf16_t;
typedef __attribute__((ext_vector_type(8))) __bf16 bf16x8;
typedef __attribute__((ext_vector_type(4))) __bf16 bf16x4;
typedef __attribute__((ext_vector_type(4))) float f32x4;

// ---- workspace layout (float offsets) ----
#define OFF_S      0u          // 8*256 rowsums of Xj
#define OFF_SI     2048u       // 8*256 rowsums of Xi
#define OFF_AB     4096u       // A = Ww@gw  bf16 [256][256]
#define OFF_BMT    36864u      // BmT = thw^T@phw bf16 [256][256]
#define OFF_T1     69632u
#define OFF_R      69888u
#define OFF_W1     70144u
#define OFF_C1     70400u
#define OFF_G      70656u      // G  bf16 8x65536 (262144 floats)
#define OFF_GX     332800u     // Gxi bf16 8x65536 (262144 floats)
#define OFF_MP     594944u     // M' bf16 8x65536 (262144 floats)
#define OFF_E      857088u     // e 8x256
#define OFF_D      859136u     // D = diag(M' Gxi M'^T) 8x256
#define OFF_RSP    861184u     // xj rowsum partials 8x16x256
#define OFF_RSPX   893952u     // xi rowsum partials 8x16x256
#define OFF_SCALE  926720u
#define OFF_SHIFT  926976u
#define OFF_GP     927232u     // xj Gram partials bf16 8*16*65536 (4194304 floats)
#define OFF_GPX    5121536u    // xi Gram partials bf16 (4194304 floats)
#define OFF_XIT    9315840u    // Xi_t bf16 8*4096*256 (4194304 floats)

__device__ __forceinline__ void pack8(const float4& x, const float4& y, bf16x8& o) {
  o[0]=(bf16_t)x.x; o[1]=(bf16_t)x.y; o[2]=(bf16_t)x.z; o[3]=(bf16_t)x.w;
  o[4]=(bf16_t)y.x; o[5]=(bf16_t)y.y; o[6]=(bf16_t)y.z; o[7]=(bf16_t)y.w;
}

__device__ __forceinline__ void ld4(const float* p, float4& a0, float4& a1, float4& a2, float4& a3) {
  a0 = *(const float4*)p;       a1 = *(const float4*)(p + 4);
  a2 = *(const float4*)(p + 8); a3 = *(const float4*)(p + 12);
}

// ---------- 64x64-tile NN/TN fp32 matmul over K=256, 512 threads ----------
template <bool ATRANS>
__device__ __forceinline__ void mm64v(const float* __restrict__ A,
                                      const float* __restrict__ B,
                                      int i0, int j0,
                                      float (&acc)[2][4],
                                      float (*s1)[65], float (*s2)[65]) {
  const int t = threadIdx.x, tx = t & 15, ty = t >> 4;
  for (int k0 = 0; k0 < 256; k0 += 64) {
#pragma unroll
    for (int it = 0; it < 2; ++it) {
      const int f = t + 512 * it;
      const int row = f >> 4, cc = (f & 15) * 4;
      float4 va;
      if (ATRANS)
        va = *(const float4*)(A + (size_t)(k0 + row) * CCH + i0 + cc);
      else
        va = *(const float4*)(A + (size_t)(i0 + row) * CCH + k0 + cc);
      const float4 vb = *(const float4*)(B + (size_t)(k0 + row) * CCH + j0 + cc);
      s1[row][cc + 0] = va.x; s1[row][cc + 1] = va.y; s1[row][cc + 2] = va.z; s1[row][cc + 3] = va.w;
      s2[row][cc + 0] = vb.x; s2[row][cc + 1] = vb.y; s2[row][cc + 2] = vb.z; s2[row][cc + 3] = vb.w;
    }
    __syncthreads();
#pragma unroll 4
    for (int kk = 0; kk < 64; ++kk) {
      float ar[2], br[4];
#pragma unroll
      for (int i = 0; i < 2; ++i) ar[i] = ATRANS ? s1[kk][2 * ty + i] : s1[2 * ty + i][kk];
#pragma unroll
      for (int j = 0; j < 4; ++j) br[j] = s2[kk][4 * tx + j];
#pragma unroll
      for (int i = 0; i < 2; ++i)
#pragma unroll
        for (int j = 0; j < 4; ++j) acc[i][j] += ar[i] * br[j];
    }
    __syncthreads();
  }
}

// ---------- mega bodies (512 threads each) ----------
__device__ void pre_body(int blk, const float* Ww, const float* gw, const float* phw,
                         const float* thw, const float* gb, const float* phb,
                         const float* thb, float* ws, unsigned char* SMEM) {
  const int t = threadIdx.x;
  if (blk < 32) {
    float (*s1)[65] = (float(*)[65])SMEM;
    float (*s2)[65] = (float(*)[65])(SMEM + 16640);
    const int tb = blk & 15;
    const int i0 = (tb >> 2) * 64, j0 = (tb & 3) * 64;
    float acc[2][4] = {};
    if (blk < 16) mm64v<false>(Ww, gw, i0, j0, acc, s1, s2);   // A = Ww@gw
    else          mm64v<true >(thw, phw, i0, j0, acc, s1, s2); // BmT = thw^T@phw
    bf16_t* outp = (bf16_t*)(ws + (blk < 16 ? OFF_AB : OFF_BMT));
    const int tx = t & 15, ty = t >> 4;
#pragma unroll
    for (int i = 0; i < 2; ++i) {
      bf16x4 mv;
#pragma unroll
      for (int q = 0; q < 4; ++q) mv[q] = (bf16_t)acc[i][q];
      *(bf16x4*)&outp[(size_t)(i0 + 2 * ty + i) * CCH + j0 + 4 * tx] = mv;
    }
  } else {
    if (t < 256) {
      float t1v = 0.f, rv = 0.f, w1v = 0.f;
      for (int k = 0; k < 256; ++k) {
        t1v += phw[k * CCH + t] * thb[k];
        rv  += thw[k * CCH + t] * phb[k];
        w1v += Ww[t * CCH + k] * gb[k];
      }
      ws[OFF_T1 + t] = t1v; ws[OFF_R + t] = rv; ws[OFF_W1 + t] = w1v;
    }
    float* red = (float*)SMEM;
    red[t] = (t < 256) ? phb[t] * thb[t] : 0.f;
    __syncthreads();
    for (int off = 256; off; off >>= 1) { if (t < off) red[t] += red[t + off]; __syncthreads(); }
    if (t == 0) ws[OFF_C1] = red[0];
  }
}

__device__ void cvtT_body(int bx, int b, const float* __restrict__ xi,
                          float* __restrict__ ws, unsigned char* SMEM) {
  bf16_t (*st)[72] = (bf16_t(*)[72])SMEM;     // [128 c][72 n]
  const int c0 = (bx & 1) * 128;
  const int n0 = (bx >> 1) * 64;
  const float* X = xi + (size_t)b * CCH * NPIX;
  const int t = threadIdx.x;
  const int r = t >> 2, c4 = (t & 3) * 16;
  {
    float4 a0, a1, a2, a3;
    ld4(X + (size_t)(c0 + r) * NPIX + n0 + c4, a0, a1, a2, a3);
    bf16x8 u0, u1;
    pack8(a0, a1, u0); pack8(a2, a3, u1);
    *(bf16x8*)&st[r][c4] = u0;
    *(bf16x8*)&st[r][c4 + 8] = u1;
  }
  __syncthreads();
  bf16_t* Xit = (bf16_t*)(ws + OFF_XIT) + (size_t)b * NPIX * CCH;
  const int nr = t >> 3, cc = (t & 7) * 16;
  bf16x8 o0, o1;
#pragma unroll
  for (int j = 0; j < 8; ++j) o0[j] = st[cc + j][nr];
#pragma unroll
  for (int j = 0; j < 8; ++j) o1[j] = st[cc + 8 + j][nr];
  *(bf16x8*)(Xit + (size_t)(n0 + nr) * CCH + c0 + cc) = o0;
  *(bf16x8*)(Xit + (size_t)(n0 + nr) * CCH + c0 + cc + 8) = o1;
}

// fused full-matrix gram: one block per (src, b, ks); reads 256 rows x 256 k once
__device__ void gram_body(int ks, int b, const float* __restrict__ X,
                          float* __restrict__ ws, unsigned char* SMEM,
                          unsigned gp_off, unsigned rsp_off) {
  bf16_t (*sA)[256][40] = (bf16_t(*)[256][40])SMEM;    // [2][256][40] = 40960 B
  const int t = threadIdx.x;
  const int w = t >> 6, lane = t & 63;
  const int wr = w >> 1, wc = w & 1;
  const int lr = lane & 15, hi = lane >> 4;
  const int fcol = 8 * hi;
  const f32x4 z4 = {0.f, 0.f, 0.f, 0.f};
  f32x4 acc[4][8];
#pragma unroll
  for (int fr = 0; fr < 4; ++fr)
#pragma unroll
    for (int fc = 0; fc < 8; ++fc) acc[fr][fc] = z4;
  float rsum = 0.f;
  const int k0 = ks * 256;
  const int srow = t >> 1, sh16 = (t & 1) * 16;

  float4 a0, a1, a2, a3;
  auto LOAD = [&](int kc) {
    ld4(X + (size_t)srow * NPIX + k0 + kc + sh16, a0, a1, a2, a3);
    rsum += a0.x + a0.y + a0.z + a0.w + a1.x + a1.y + a1.z + a1.w
          + a2.x + a2.y + a2.z + a2.w + a3.x + a3.y + a3.z + a3.w;
  };
  auto WRITE = [&](int q) {
    bf16x8 u0, u1;
    pack8(a0, a1, u0); pack8(a2, a3, u1);
    *(bf16x8*)&sA[q][srow][sh16] = u0;
    *(bf16x8*)&sA[q][srow][sh16 + 8] = u1;
  };

  LOAD(0);
  WRITE(0);
  __syncthreads();
  int cur = 0;
  for (int kc8 = 0; kc8 < 8; ++kc8) {
    if (kc8 < 7) LOAD(32 * (kc8 + 1));
    bf16x8 af[4];
#pragma unroll
    for (int fr = 0; fr < 4; ++fr)
      af[fr] = *(const bf16x8*)&sA[cur][64 * wr + 16 * fr + lr][fcol];
#pragma unroll
    for (int fc = 0; fc < 8; ++fc) {
      const bf16x8 bv = *(const bf16x8*)&sA[cur][128 * wc + 16 * fc + lr][fcol];
#pragma unroll
      for (int fr = 0; fr < 4; ++fr)
        acc[fr][fc] = __builtin_amdgcn_mfma_f32_16x16x32_bf16(af[fr], bv, acc[fr][fc], 0, 0, 0);
    }
    if (kc8 < 7) WRITE(cur ^ 1);
    __syncthreads();
    cur ^= 1;
  }

  {
    const float o = __shfl_down(rsum, 1);
    if (!(t & 1)) ws[rsp_off + ((size_t)(b * 16 + ks)) * CCH + srow] = rsum + o;
  }
  bf16_t* GPp = (bf16_t*)(ws + gp_off) + (size_t)(b * 16 + ks) * 65536;
#pragma unroll
  for (int fr = 0; fr < 4; ++fr)
#pragma unroll
    for (int fc = 0; fc < 8; ++fc)
#pragma unroll
      for (int reg = 0; reg < 4; ++reg)
        GPp[(size_t)(64 * wr + 16 * fr + 4 * hi + reg) * CCH + 128 * wc + 16 * fc + lr] =
            (bf16_t)acc[fr][fc][reg];
}

// ---------- mega: gram_xj (x<16) | gram_xi (16<=x<32) | cvtT (32<=x<160) | pre (x>=160) ----------
__global__ __launch_bounds__(512) void k_mega(const float* __restrict__ xi,
                                              const float* __restrict__ xj,
                                              const float* __restrict__ Ww,
                                              const float* __restrict__ gw,
                                              const float* __restrict__ phw,
                                              const float* __restrict__ thw,
                                              const float* __restrict__ gb,
                                              const float* __restrict__ phb,
                                              const float* __restrict__ thb,
                                              float* __restrict__ ws) {
  __shared__ __align__(16) unsigned char SMEM[40960];
  const int bx = blockIdx.x, by = blockIdx.y;
  if (bx >= 160) {
    if (by == 0) pre_body(bx - 160, Ww, gw, phw, thw, gb, phb, thb, ws, SMEM);
    return;
  }
  if (bx >= 32) { cvtT_body(bx - 32, by, xi, ws, SMEM); return; }
  if (bx < 16)
    gram_body(bx, by, xj + (size_t)by * CCH * NPIX, ws, SMEM, OFF_GP, OFF_RSP);
  else
    gram_body(bx - 16, by, xi + (size_t)by * CCH * NPIX, ws, SMEM, OFF_GPX, OFF_RSPX);
}

// ---------- reduce 16 bf16 Gram partials -> G/GX bf16; finalize rowsums ----------
__global__ __launch_bounds__(256) void k_greduce(float* __restrict__ ws) {
  const int b = blockIdx.y, bx = blockIdx.x, t = threadIdx.x;
  const bool isX = bx >= 32;
  const int bxl = bx & 31;
  const bf16_t* GPp = (const bf16_t*)(ws + (isX ? OFF_GPX : OFF_GP)) + (size_t)b * 16 * 65536;
  bf16_t* Gb = (bf16_t*)(ws + (isX ? OFF_GX : OFF_G)) + (size_t)b * 65536;
  const int row = bxl * 8 + (t >> 5);
  const int j8 = (t & 31) * 8;
  float s[8] = {};
#pragma unroll
  for (int ks = 0; ks < 16; ++ks) {
    const bf16x8 v = *(const bf16x8*)&GPp[(size_t)ks * 65536 + row * CCH + j8];
#pragma unroll
    for (int q = 0; q < 8; ++q) s[q] += (float)v[q];
  }
  bf16x8 o;
#pragma unroll
  for (int q = 0; q < 8; ++q) o[q] = (bf16_t)s[q];
  *(bf16x8*)&Gb[(size_t)row * CCH + j8] = o;
  if (t < 128) {
    const int rr = bxl * 8 + (t >> 4), l = t & 15;
    float v = ws[(isX ? OFF_RSPX : OFF_RSP) + ((size_t)(b * 16 + l)) * CCH + rr];
#pragma unroll
    for (int off = 8; off; off >>= 1) v += __shfl_down(v, off, 16);
    if (l == 0) ws[(isX ? OFF_SI : OFF_S) + b * CCH + rr] = v;
  }
}

// ---------- fused K=A@G, e, M'=f(K@Bm), D=diag(M' Gxi M'^T); 32-row blocks ----------
__global__ __launch_bounds__(256) void k_kmmat(const float* __restrict__ Wb, float* __restrict__ ws) {
  const int b = blockIdx.y;
  const int i0 = blockIdx.x * 32;
  const int t = threadIdx.x;
  const int w = t >> 6, lane = t & 63;
  const int rg = w >> 1, cg = w & 1;
  const int lr = lane & 15, hi = lane >> 4;
  const int fcol = 8 * hi;

  __shared__ __align__(16) bf16_t sA[2][32][40];
  __shared__ __align__(16) bf16_t sB[2][256][40];
  __shared__ __align__(16) bf16_t sK[32][264];      // K in phases B/C; M' in phase D
  __shared__ float sS[256], sT1[256], sR[256], sW1[256], sVS[256];
  __shared__ float sU[32];
  __shared__ float red[256];
  __shared__ float redD[2][32];
  __shared__ float sdt_sh;

  const bf16_t* Ab  = (const bf16_t*)(ws + OFF_AB);
  const bf16_t* BmT = (const bf16_t*)(ws + OFF_BMT);
  const bf16_t* Gb  = (const bf16_t*)(ws + OFF_G) + (size_t)b * 65536;
  const bf16_t* Gxb = (const bf16_t*)(ws + OFF_GX) + (size_t)b * 65536;

  sS[t]  = ws[OFF_S + b * CCH + t];
  sT1[t] = ws[OFF_T1 + t];
  sR[t]  = ws[OFF_R + t];
  sW1[t] = ws[OFF_W1 + t];
  __syncthreads();
  red[t] = sS[t] * sT1[t];
  __syncthreads();
  for (int off = 128; off; off >>= 1) { if (t < off) red[t] += red[t + off]; __syncthreads(); }
  if (t == 0) sdt_sh = red[0];
  {
    float a = 0.f;
    for (int k8 = 0; k8 < 256; k8 += 8) {
      const bf16x8 v = *(const bf16x8*)&BmT[(size_t)t * CCH + k8];
#pragma unroll
      for (int q = 0; q < 8; ++q) a += (float)v[q] * sS[k8 + q];
    }
    sVS[t] = a;
  }
  if (t < 32) {
    float a = 0.f;
    for (int k8 = 0; k8 < 256; k8 += 8) {
      const bf16x8 v = *(const bf16x8*)&Ab[(size_t)(i0 + t) * CCH + k8];
#pragma unroll
      for (int q = 0; q < 8; ++q) a += (float)v[q] * sS[k8 + q];
    }
    sU[t] = a;
  }

  const f32x4 z4 = {0.f, 0.f, 0.f, 0.f};
  const int arow = t >> 2, achk = (t & 3) * 8;

  // ---- phase B: K = A @ G (G symmetric) ----
  f32x4 acc[8];
#pragma unroll
  for (int fc = 0; fc < 8; ++fc) acc[fc] = z4;
  bf16x8 ra;
  bf16x8 gb8[4];
  auto LOADB = [&](int k) {
    if (t < 128) ra = *(const bf16x8*)&Ab[(size_t)(i0 + arow) * CCH + k + achk];
#pragma unroll
    for (int h = 0; h < 4; ++h)
      gb8[h] = *(const bf16x8*)&Gb[(size_t)(64 * h + arow) * CCH + k + achk];
  };
  auto WRITEB = [&](int q) {
    if (t < 128) *(bf16x8*)&sA[q][arow][achk] = ra;
#pragma unroll
    for (int h = 0; h < 4; ++h)
      *(bf16x8*)&sB[q][64 * h + arow][achk] = gb8[h];
  };
  LOADB(0);
  WRITEB(0);
  __syncthreads();
  int cur = 0;
  for (int ks = 0; ks < 8; ++ks) {
    if (ks < 7) LOADB(32 * (ks + 1));
    const bf16x8 af = *(const bf16x8*)&sA[cur][16 * rg + lr][fcol];
#pragma unroll
    for (int fc = 0; fc < 8; ++fc) {
      const bf16x8 bv = *(const bf16x8*)&sB[cur][128 * cg + 16 * fc + lr][fcol];
      acc[fc] = __builtin_amdgcn_mfma_f32_16x16x32_bf16(af, bv, acc[fc], 0, 0, 0);
    }
    if (ks < 7) WRITEB(cur ^ 1);
    __syncthreads();
    cur ^= 1;
  }
  // K -> LDS bf16
#pragma unroll
  for (int fc = 0; fc < 8; ++fc)
#pragma unroll
    for (int reg = 0; reg < 4; ++reg)
      sK[16 * rg + 4 * hi + reg][128 * cg + 16 * fc + lr] = (bf16_t)acc[fc][reg];
  __syncthreads();

  // e (t<32)
  if (t < 32) {
    float dot = 0.f;
    for (int k8 = 0; k8 < 256; k8 += 8) {
      const bf16x8 v = *(const bf16x8*)&sK[t][k8];
#pragma unroll
      for (int q = 0; q < 8; ++q) dot += (float)v[q] * sT1[k8 + q];
    }
    const float c1 = ws[OFF_C1];
    const float ui = sU[t], w1i = sW1[i0 + t];
    ws[OFF_E + b * CCH + i0 + t] = INVN * (dot + c1 * ui + sdt_sh * w1i) + c1 * w1i + Wb[i0 + t];
  }

  // ---- phase C: Mcore = K @ Bm ----
  f32x4 acc2[8];
#pragma unroll
  for (int fc = 0; fc < 8; ++fc) acc2[fc] = z4;
  bf16x8 rb[4];
  auto LOADC = [&](int k) {
#pragma unroll
    for (int h = 0; h < 4; ++h)
      rb[h] = *(const bf16x8*)&BmT[(size_t)(64 * h + arow) * CCH + k + achk];
  };
  auto WRITEC = [&](int q) {
#pragma unroll
    for (int h = 0; h < 4; ++h)
      *(bf16x8*)&sB[q][64 * h + arow][achk] = rb[h];
  };
  LOADC(0);
  WRITEC(0);
  __syncthreads();
  cur = 0;
  for (int ks = 0; ks < 8; ++ks) {
    if (ks < 7) LOADC(32 * (ks + 1));
    const bf16x8 af = *(const bf16x8*)&sK[16 * rg + lr][32 * ks + fcol];
#pragma unroll
    for (int fc = 0; fc < 8; ++fc) {
      const bf16x8 bv = *(const bf16x8*)&sB[cur][128 * cg + 16 * fc + lr][fcol];
      acc2[fc] = __builtin_amdgcn_mfma_f32_16x16x32_bf16(af, bv, acc2[fc], 0, 0, 0);
    }
    if (ks < 7) WRITEC(cur ^ 1);
    __syncthreads();
    cur ^= 1;
  }

  // epilogue: M' = (acc2 + u r^T + w1 vs^T)/N + w1 r^T + I  (bf16)
  bf16_t* Mp = (bf16_t*)(ws + OFF_MP) + (size_t)b * 65536;
  float mreg[8][4];
#pragma unroll
  for (int fc = 0; fc < 8; ++fc) {
    const int j = 128 * cg + 16 * fc + lr;
    const float rj = sR[j], vsj = sVS[j];
#pragma unroll
    for (int reg = 0; reg < 4; ++reg) {
      const int il = 16 * rg + 4 * hi + reg;
      const float ui = sU[il], w1i = sW1[i0 + il];
      float m = (acc2[fc][reg] + ui * rj + w1i * vsj) * INVN + w1i * rj;
      if (i0 + il == j) m += 1.0f;
      const bf16_t mb = (bf16_t)m;
      Mp[(size_t)(i0 + il) * CCH + j] = mb;
      mreg[fc][reg] = (float)mb;
    }
  }
  // M' -> sK buffer (reuse) for phase D A-operand
#pragma unroll
  for (int fc = 0; fc < 8; ++fc)
#pragma unroll
    for (int reg = 0; reg < 4; ++reg)
      sK[16 * rg + 4 * hi + reg][128 * cg + 16 * fc + lr] = (bf16_t)mreg[fc][reg];
  __syncthreads();

  // ---- phase D: P = M' @ Gxi (Gxi symmetric); D = rowdot(P, M') ----
  f32x4 acc3[8];
#pragma unroll
  for (int fc = 0; fc < 8; ++fc) acc3[fc] = z4;
  auto LOADD = [&](int k) {
#pragma unroll
    for (int h = 0; h < 4; ++h)
      gb8[h] = *(const bf16x8*)&Gxb[(size_t)(64 * h + arow) * CCH + k + achk];
  };
  auto WRITED = [&](int q) {
#pragma unroll
    for (int h = 0; h < 4; ++h)
      *(bf16x8*)&sB[q][64 * h + arow][achk] = gb8[h];
  };
  LOADD(0);
  WRITED(0);
  __syncthreads();
  cur = 0;
  for (int ks = 0; ks < 8; ++ks) {
    if (ks < 7) LOADD(32 * (ks + 1));
    const bf16x8 af = *(const bf16x8*)&sK[16 * rg + lr][32 * ks + fcol];
#pragma unroll
    for (int fc = 0; fc < 8; ++fc) {
      const bf16x8 bv = *(const bf16x8*)&sB[cur][128 * cg + 16 * fc + lr][fcol];
      acc3[fc] = __builtin_amdgcn_mfma_f32_16x16x32_bf16(af, bv, acc3[fc], 0, 0, 0);
    }
    if (ks < 7) WRITED(cur ^ 1);
    __syncthreads();
    cur ^= 1;
  }
  float dpart[4] = {};
#pragma unroll
  for (int fc = 0; fc < 8; ++fc)
#pragma unroll
    for (int reg = 0; reg < 4; ++reg)
      dpart[reg] += acc3[fc][reg] * mreg[fc][reg];
#pragma unroll
  for (int reg = 0; reg < 4; ++reg) {
    float d = dpart[reg];
    d += __shfl_xor(d, 1); d += __shfl_xor(d, 2);
    d += __shfl_xor(d, 4); d += __shfl_xor(d, 8);
    dpart[reg] = d;
  }
  if (lr == 0) {
#pragma unroll
    for (int reg = 0; reg < 4; ++reg)
      redD[cg][16 * rg + 4 * hi + reg] = dpart[reg];
  }
  __syncthreads();
  if (t < 32) ws[OFF_D + b * CCH + i0 + t] = redD[0][t] + redD[1][t];
}

// ---------- BN finalize: stats from u2 = M' s_i, D, e ----------
__global__ __launch_bounds__(64) void k_bnfin(const float* __restrict__ gamma,
                                              const float* __restrict__ beta,
                                              float* __restrict__ ws) {
  const int c = blockIdx.x, t = threadIdx.x;
  __shared__ float sSI[NB][256];
  for (int i = t; i < NB * 256; i += 64) sSI[i >> 8][i & 255] = ws[OFF_SI + i];
  __syncthreads();
  float sz = 0.f, sq = 0.f;
  for (int b = 0; b < NB; ++b) {
    const bf16_t* Mrow = (const bf16_t*)(ws + OFF_MP) + (size_t)b * 65536 + (size_t)c * CCH;
    const bf16x4 v = *(const bf16x4*)&Mrow[t * 4];
    float p = 0.f;
#pragma unroll
    for (int q = 0; q < 4; ++q) p += (float)v[q] * sSI[b][t * 4 + q];
#pragma unroll
    for (int off = 1; off < 64; off <<= 1) p += __shfl_xor(p, off);
    const float e = ws[OFF_E + b * CCH + c];
    sz += p + 4096.f * e;
    sq += ws[OFF_D + b * CCH + c] + 2.f * e * p + 4096.f * e * e;
  }
  if (t == 0) {
    const float mean = sz * INVCNT;
    const float var = sq * INVCNT - mean * mean;
    const float sc = gamma[c] * rsqrtf(var + 1e-5f);
    ws[OFF_SCALE + c] = sc;
    ws[OFF_SHIFT + c] = beta[c] - mean * sc;
  }
}

// ---------- Z^T 64-n tiles via MFMA, dbuf; apply BN; write out ----------
__global__ __launch_bounds__(256) void k_zapply(float* __restrict__ ws, float* __restrict__ out) {
  const int b = blockIdx.y, nblk = blockIdx.x;
  const int n0 = nblk * 64;
  const int t = threadIdx.x;
  const int w = t >> 6, lane = t & 63;
  const int rg = w >> 1, cg = w & 1;
  __shared__ __align__(16) bf16_t sA[2][64][40];
  __shared__ __align__(16) bf16_t sB[2][256][40];
  __shared__ float sC1[256], sC2[256];
  {
    const float e = ws[OFF_E + b * CCH + t];
    const float sc = ws[OFF_SCALE + t];
    sC1[t] = sc;
    sC2[t] = e * sc + ws[OFF_SHIFT + t];
  }
  const bf16_t* Xit = (const bf16_t*)(ws + OFF_XIT) + (size_t)b * NPIX * CCH;
  const bf16_t* Mp = (const bf16_t*)(ws + OFF_MP) + (size_t)b * 65536;
  const f32x4 z4 = {0.f, 0.f, 0.f, 0.f};
  f32x4 acc[2][8];
#pragma unroll
  for (int fr = 0; fr < 2; ++fr)
#pragma unroll
    for (int fc = 0; fc < 8; ++fc) acc[fr][fc] = z4;
  const int arow = t >> 2, achk = (t & 3) * 8;
  bf16x8 ra, rb0, rb1, rb2, rb3;
  ra  = *(const bf16x8*)(Xit + (size_t)(n0 + arow) * CCH + achk);
  rb0 = *(const bf16x8*)(Mp + (size_t)(arow)       * CCH + achk);
  rb1 = *(const bf16x8*)(Mp + (size_t)(64 + arow)  * CCH + achk);
  rb2 = *(const bf16x8*)(Mp + (size_t)(128 + arow) * CCH + achk);
  rb3 = *(const bf16x8*)(Mp + (size_t)(192 + arow) * CCH + achk);
  *(bf16x8*)&sA[0][arow][achk] = ra;
  *(bf16x8*)&sB[0][arow][achk] = rb0;
  *(bf16x8*)&sB[0][64 + arow][achk] = rb1;
  *(bf16x8*)&sB[0][128 + arow][achk] = rb2;
  *(bf16x8*)&sB[0][192 + arow][achk] = rb3;
  __syncthreads();
  int cur = 0;
  for (int ks = 0; ks < 8; ++ks) {
    const int nk = 32 * (ks + 1);
    if (ks < 7) {
      ra  = *(const bf16x8*)(Xit + (size_t)(n0 + arow) * CCH + nk + achk);
      rb0 = *(const bf16x8*)(Mp + (size_t)(arow)       * CCH + nk + achk);
      rb1 = *(const bf16x8*)(Mp + (size_t)(64 + arow)  * CCH + nk + achk);
      rb2 = *(const bf16x8*)(Mp + (size_t)(128 + arow) * CCH + nk + achk);
      rb3 = *(const bf16x8*)(Mp + (size_t)(192 + arow) * CCH + nk + achk);
    }
    const int fcol = 8 * (lane >> 4);
    const int lr = lane & 15;
    const bf16x8 af0 = *(const bf16x8*)&sA[cur][32 * rg + lr][fcol];
    const bf16x8 af1 = *(const bf16x8*)&sA[cur][32 * rg + 16 + lr][fcol];
#pragma unroll
    for (int fc = 0; fc < 8; ++fc) {
      const bf16x8 bv = *(const bf16x8*)&sB[cur][128 * cg + 16 * fc + lr][fcol];
      acc[0][fc] = __builtin_amdgcn_mfma_f32_16x16x32_bf16(af0, bv, acc[0][fc], 0, 0, 0);
      acc[1][fc] = __builtin_amdgcn_mfma_f32_16x16x32_bf16(af1, bv, acc[1][fc], 0, 0, 0);
    }
    if (ks < 7) {
      *(bf16x8*)&sA[cur ^ 1][arow][achk] = ra;
      *(bf16x8*)&sB[cur ^ 1][arow][achk] = rb0;
      *(bf16x8*)&sB[cur ^ 1][64 + arow][achk] = rb1;
      *(bf16x8*)&sB[cur ^ 1][128 + arow][achk] = rb2;
      *(bf16x8*)&sB[cur ^ 1][192 + arow][achk] = rb3;
    }
    __syncthreads();
    cur ^= 1;
  }
#pragma unroll
  for (int fc = 0; fc < 8; ++fc) {
    const int c = 128 * cg + 16 * fc + (lane & 15);
    const float sc = sC1[c], b2 = sC2[c];
    float* op = out + ((size_t)b * CCH + c) * NPIX + n0 + 32 * rg + ((lane >> 4) << 2);
#pragma unroll
    for (int fr = 0; fr < 2; ++fr) {
      float4 v;
      v.x = acc[fr][fc][0] * sc + b2;
      v.y = acc[fr][fc][1] * sc + b2;
      v.z = acc[fr][fc][2] * sc + b2;
      v.w = acc[fr][fc][3] * sc + b2;
      *(float4*)(op + 16 * fr) = v;
    }
  }
}

extern "C" void kernel_launch(void* const* d_in, const int* in_sizes, int n_in,
                              void* d_out, int out_size, void* d_ws, size_t ws_size,
                              hipStream_t stream) {
  const float* xi  = (const float*)d_in[0];
  const float* xj  = (const float*)d_in[1];
  const float* gw  = (const float*)d_in[2];
  const float* gb  = (const float*)d_in[3];
  const float* thw = (const float*)d_in[4];
  const float* thb = (const float*)d_in[5];
  const float* phw = (const float*)d_in[6];
  const float* phb = (const float*)d_in[7];
  const float* Ww  = (const float*)d_in[8];
  const float* Wb  = (const float*)d_in[9];
  const float* gamma = (const float*)d_in[10];
  const float* beta  = (const float*)d_in[11];
  float* ws = (float*)d_ws;
  float* out = (float*)d_out;

  k_mega<<<dim3(193, 8), 512, 0, stream>>>(xi, xj, Ww, gw, phw, thw, gb, phb, thb, ws);
  k_greduce<<<dim3(64, 8), 256, 0, stream>>>(ws);
  k_kmmat<<<dim3(8, 8), 256, 0, stream>>>(Wb, ws);
  k_bnfin<<<256, 64, 0, stream>>>(gamma, beta, ws);
  k_zapply<<<dim3(64, 8), 256, 0, stream>>>(ws, out);
}

// Round 10
// 87.967 us; speedup vs baseline: 1.1428x; 1.1428x over previous
//
#include <hip/hip_runtime.h>
#include <cstddef>

#define CCH 256
#define NPIX 4096
#define NB 8
#define INVCNT (1.0f/32768.0f)
#define INVN (1.0f/4096.0f)

typedef __bf16 bf16_t;
typedef __attribute__((ext_vector_type(8))) __bf16 bf16x8;
typedef __attribute__((ext_vector_type(4))) __bf16 bf16x4;
typedef __attribute__((ext_vector_type(4))) float f32x4;

// ---- workspace layout (float offsets) ----
#define OFF_S      0u          // 8*256 rowsums of Xj
#define OFF_AB     2048u       // A = Ww@gw  bf16 [256][256]
#define OFF_BMT    34816u      // BmT = thw^T@phw bf16 [256][256]
#define OFF_T1     67584u
#define OFF_R      67840u
#define OFF_W1     68096u
#define OFF_C1     68352u
#define OFF_G      68608u      // G bf16 8 x 256x256 (262144 floats)
#define OFF_MP     330752u     // M' bf16 8x65536 (262144 floats)
#define OFF_E      592896u     // e 8x256
#define OFF_RSP    594944u     // rowsum partials 8x16x256 (32768)
#define OFF_ZPS    627712u     // bn partial sums  [c 256][entry 512]
#define OFF_ZPQ    758784u     // bn partial sumsq [c 256][entry 512]
#define OFF_SCALE  889856u
#define OFF_SHIFT  890112u
#define OFF_GP     890368u     // Gram partials bf16 8*16*65536 el (4194304 floats)
#define OFF_XIT    5084672u    // Xi_t bf16 8*4096*256 (4194304 floats)

__device__ __forceinline__ void pack8(const float4& x, const float4& y, bf16x8& o) {
  o[0]=(bf16_t)x.x; o[1]=(bf16_t)x.y; o[2]=(bf16_t)x.z; o[3]=(bf16_t)x.w;
  o[4]=(bf16_t)y.x; o[5]=(bf16_t)y.y; o[6]=(bf16_t)y.z; o[7]=(bf16_t)y.w;
}

__device__ __forceinline__ void ld4(const float* p, float4& a0, float4& a1, float4& a2, float4& a3) {
  a0 = *(const float4*)p;       a1 = *(const float4*)(p + 4);
  a2 = *(const float4*)(p + 8); a3 = *(const float4*)(p + 12);
}

// ---------- 64x64-tile NN/TN fp32 matmul over K=256, 512 threads ----------
template <bool ATRANS>
__device__ __forceinline__ void mm64v(const float* __restrict__ A,
                                      const float* __restrict__ B,
                                      int i0, int j0,
                                      float (&acc)[2][4],
                                      float (*s1)[65], float (*s2)[65]) {
  const int t = threadIdx.x, tx = t & 15, ty = t >> 4;   // ty 0..31 -> rows 2ty,2ty+1
  for (int k0 = 0; k0 < 256; k0 += 64) {
#pragma unroll
    for (int it = 0; it < 2; ++it) {
      const int f = t + 512 * it;
      const int row = f >> 4, cc = (f & 15) * 4;
      float4 va;
      if (ATRANS)
        va = *(const float4*)(A + (size_t)(k0 + row) * CCH + i0 + cc);
      else
        va = *(const float4*)(A + (size_t)(i0 + row) * CCH + k0 + cc);
      const float4 vb = *(const float4*)(B + (size_t)(k0 + row) * CCH + j0 + cc);
      s1[row][cc + 0] = va.x; s1[row][cc + 1] = va.y; s1[row][cc + 2] = va.z; s1[row][cc + 3] = va.w;
      s2[row][cc + 0] = vb.x; s2[row][cc + 1] = vb.y; s2[row][cc + 2] = vb.z; s2[row][cc + 3] = vb.w;
    }
    __syncthreads();
#pragma unroll 4
    for (int kk = 0; kk < 64; ++kk) {
      float ar[2], br[4];
#pragma unroll
      for (int i = 0; i < 2; ++i) ar[i] = ATRANS ? s1[kk][2 * ty + i] : s1[2 * ty + i][kk];
#pragma unroll
      for (int j = 0; j < 4; ++j) br[j] = s2[kk][4 * tx + j];
#pragma unroll
      for (int i = 0; i < 2; ++i)
#pragma unroll
        for (int j = 0; j < 4; ++j) acc[i][j] += ar[i] * br[j];
    }
    __syncthreads();
  }
}

// ---------- mega bodies (512 threads each) ----------
__device__ void pre_body(int blk, const float* Ww, const float* gw, const float* phw,
                         const float* thw, const float* gb, const float* phb,
                         const float* thb, float* ws, unsigned char* SMEM) {
  const int t = threadIdx.x;
  if (blk < 32) {
    float (*s1)[65] = (float(*)[65])SMEM;
    float (*s2)[65] = (float(*)[65])(SMEM + 16640);
    const int tb = blk & 15;
    const int i0 = (tb >> 2) * 64, j0 = (tb & 3) * 64;
    float acc[2][4] = {};
    if (blk < 16) mm64v<false>(Ww, gw, i0, j0, acc, s1, s2);   // A = Ww@gw
    else          mm64v<true >(thw, phw, i0, j0, acc, s1, s2); // BmT = thw^T@phw
    bf16_t* outp = (bf16_t*)(ws + (blk < 16 ? OFF_AB : OFF_BMT));
    const int tx = t & 15, ty = t >> 4;
#pragma unroll
    for (int i = 0; i < 2; ++i) {
      bf16x4 mv;
#pragma unroll
      for (int q = 0; q < 4; ++q) mv[q] = (bf16_t)acc[i][q];
      *(bf16x4*)&outp[(size_t)(i0 + 2 * ty + i) * CCH + j0 + 4 * tx] = mv;
    }
  } else {
    if (t < 256) {
      float t1v = 0.f, rv = 0.f, w1v = 0.f;
      for (int k = 0; k < 256; ++k) {
        t1v += phw[k * CCH + t] * thb[k];
        rv  += thw[k * CCH + t] * phb[k];
        w1v += Ww[t * CCH + k] * gb[k];
      }
      ws[OFF_T1 + t] = t1v; ws[OFF_R + t] = rv; ws[OFF_W1 + t] = w1v;
    }
    float* red = (float*)SMEM;
    red[t] = (t < 256) ? phb[t] * thb[t] : 0.f;
    __syncthreads();
    for (int off = 256; off; off >>= 1) { if (t < off) red[t] += red[t + off]; __syncthreads(); }
    if (t == 0) ws[OFF_C1] = red[0];
  }
}

__device__ void cvtT_body(int bx, int b, const float* __restrict__ xi,
                          float* __restrict__ ws, unsigned char* SMEM) {
  bf16_t (*st)[72] = (bf16_t(*)[72])SMEM;     // [128 c][72 n]
  const int c0 = (bx & 1) * 128;
  const int n0 = (bx >> 1) * 64;
  const float* X = xi + (size_t)b * CCH * NPIX;
  const int t = threadIdx.x;
  const int r = t >> 2, c4 = (t & 3) * 16;
  {
    float4 a0, a1, a2, a3;
    ld4(X + (size_t)(c0 + r) * NPIX + n0 + c4, a0, a1, a2, a3);
    bf16x8 u0, u1;
    pack8(a0, a1, u0); pack8(a2, a3, u1);
    *(bf16x8*)&st[r][c4] = u0;
    *(bf16x8*)&st[r][c4 + 8] = u1;
  }
  __syncthreads();
  bf16_t* Xit = (bf16_t*)(ws + OFF_XIT) + (size_t)b * NPIX * CCH;
  const int nr = t >> 3, cc = (t & 7) * 16;
  bf16x8 o0, o1;
#pragma unroll
  for (int j = 0; j < 8; ++j) o0[j] = st[cc + j][nr];
#pragma unroll
  for (int j = 0; j < 8; ++j) o1[j] = st[cc + 8 + j][nr];
  *(bf16x8*)(Xit + (size_t)(n0 + nr) * CCH + c0 + cc) = o0;
  *(bf16x8*)(Xit + (size_t)(n0 + nr) * CCH + c0 + cc + 8) = o1;
}

// fused full-matrix gram: one block per (b, ks); reads 256 rows x 256 k once.
// Epilogue: LDS-bounce (64-row chunks; R9 bug was a 32-row sT with 64-row writes)
// -> vectorized bf16x8 stores.
__device__ void gram_body(int ks, int b, const float* __restrict__ X,
                          float* __restrict__ ws, unsigned char* SMEM) {
  bf16_t (*sA)[256][40] = (bf16_t(*)[256][40])SMEM;    // [2][256][40] = 40960 B
  const int t = threadIdx.x;
  const int w = t >> 6, lane = t & 63;
  const int wr = w >> 1, wc = w & 1;
  const int lr = lane & 15, hi = lane >> 4;
  const int fcol = 8 * hi;
  const f32x4 z4 = {0.f, 0.f, 0.f, 0.f};
  f32x4 acc[4][8];
#pragma unroll
  for (int fr = 0; fr < 4; ++fr)
#pragma unroll
    for (int fc = 0; fc < 8; ++fc) acc[fr][fc] = z4;
  float rsum = 0.f;
  const int k0 = ks * 256;
  const int srow = t >> 1, sh16 = (t & 1) * 16;

  float4 a0, a1, a2, a3;
  auto LOAD = [&](int kc) {
    ld4(X + (size_t)srow * NPIX + k0 + kc + sh16, a0, a1, a2, a3);
    rsum += a0.x + a0.y + a0.z + a0.w + a1.x + a1.y + a1.z + a1.w
          + a2.x + a2.y + a2.z + a2.w + a3.x + a3.y + a3.z + a3.w;
  };
  auto WRITE = [&](int q) {
    bf16x8 u0, u1;
    pack8(a0, a1, u0); pack8(a2, a3, u1);
    *(bf16x8*)&sA[q][srow][sh16] = u0;
    *(bf16x8*)&sA[q][srow][sh16 + 8] = u1;
  };

  LOAD(0);
  WRITE(0);
  __syncthreads();
  int cur = 0;
  for (int kc8 = 0; kc8 < 8; ++kc8) {
    if (kc8 < 7) LOAD(32 * (kc8 + 1));
    bf16x8 af[4];
#pragma unroll
    for (int fr = 0; fr < 4; ++fr)
      af[fr] = *(const bf16x8*)&sA[cur][64 * wr + 16 * fr + lr][fcol];
#pragma unroll
    for (int fc = 0; fc < 8; ++fc) {
      const bf16x8 bv = *(const bf16x8*)&sA[cur][128 * wc + 16 * fc + lr][fcol];
#pragma unroll
      for (int fr = 0; fr < 4; ++fr)
        acc[fr][fc] = __builtin_amdgcn_mfma_f32_16x16x32_bf16(af[fr], bv, acc[fr][fc], 0, 0, 0);
    }
    if (kc8 < 7) WRITE(cur ^ 1);
    __syncthreads();
    cur ^= 1;
  }

  {
    const float o = __shfl_down(rsum, 1);
    if (!(t & 1)) ws[OFF_RSP + ((size_t)(b * 16 + ks)) * CCH + srow] = rsum + o;
  }
  // ---- epilogue: 4 fr-chunks, each covering 64 rows (4 wr-groups x 16) ----
  bf16_t* GPp = (bf16_t*)(ws + OFF_GP) + (size_t)(b * 16 + ks) * 65536;
  bf16_t (*sT)[264] = (bf16_t(*)[264])SMEM;   // [64][264] = 33792 B <= 40960
  const int rl = 16 * wr + 4 * hi;            // local row base: 0..60
#pragma unroll
  for (int fr = 0; fr < 4; ++fr) {
    __syncthreads();
#pragma unroll
    for (int fc = 0; fc < 8; ++fc)
#pragma unroll
      for (int reg = 0; reg < 4; ++reg)
        sT[rl + reg][128 * wc + 16 * fc + lr] = (bf16_t)acc[fr][fc][reg];
    __syncthreads();
    const int row = t >> 3;                   // 0..63
    const int c32 = (t & 7) * 32;
    const int grow = 64 * (row >> 4) + 16 * fr + (row & 15);
#pragma unroll
    for (int q = 0; q < 4; ++q) {
      const bf16x8 v = *(const bf16x8*)&sT[row][c32 + 8 * q];
      *(bf16x8*)&GPp[(size_t)grow * CCH + c32 + 8 * q] = v;
    }
  }
}

// ---------- mega: gram (x<16) | cvtT (16<=x<144) | pre (x>=144, y==0) ----------
__global__ __launch_bounds__(512) void k_mega(const float* __restrict__ xi,
                                              const float* __restrict__ xj,
                                              const float* __restrict__ Ww,
                                              const float* __restrict__ gw,
                                              const float* __restrict__ phw,
                                              const float* __restrict__ thw,
                                              const float* __restrict__ gb,
                                              const float* __restrict__ phb,
                                              const float* __restrict__ thb,
                                              float* __restrict__ ws) {
  __shared__ __align__(16) unsigned char SMEM[40960];
  const int bx = blockIdx.x, by = blockIdx.y;
  if (bx >= 144) {
    if (by == 0) pre_body(bx - 144, Ww, gw, phw, thw, gb, phb, thb, ws, SMEM);
    return;
  }
  if (bx >= 16) { cvtT_body(bx - 16, by, xi, ws, SMEM); return; }
  gram_body(bx, by, xj + (size_t)by * CCH * NPIX, ws, SMEM);
}

// ---------- reduce 16 bf16 Gram partials -> G bf16; finalize rowsums ----------
__global__ __launch_bounds__(256) void k_greduce(float* __restrict__ ws) {
  const int b = blockIdx.y, bx = blockIdx.x, t = threadIdx.x;
  const bf16_t* GPp = (const bf16_t*)(ws + OFF_GP) + (size_t)b * 16 * 65536;
  bf16_t* Gb = (bf16_t*)(ws + OFF_G) + (size_t)b * 65536;
  const int row = bx * 8 + (t >> 5);
  const int j8 = (t & 31) * 8;
  float s[8] = {};
#pragma unroll
  for (int ks = 0; ks < 16; ++ks) {
    const bf16x8 v = *(const bf16x8*)&GPp[(size_t)ks * 65536 + row * CCH + j8];
#pragma unroll
    for (int q = 0; q < 8; ++q) s[q] += (float)v[q];
  }
  bf16x8 o;
#pragma unroll
  for (int q = 0; q < 8; ++q) o[q] = (bf16_t)s[q];
  *(bf16x8*)&Gb[(size_t)row * CCH + j8] = o;
  if (t < 128) {
    const int rr = bx * 8 + (t >> 4), l = t & 15;
    float v = ws[OFF_RSP + ((size_t)(b * 16 + l)) * CCH + rr];
#pragma unroll
    for (int off = 8; off; off >>= 1) v += __shfl_down(v, off, 16);
    if (l == 0) ws[OFF_S + b * CCH + rr] = v;
  }
}

// ---------- fused K = A@G (MFMA), e, M' = f(K@Bm) (MFMA); 32-row blocks ----------
__global__ __launch_bounds__(256) void k_kmmat(const float* __restrict__ Wb, float* __restrict__ ws) {
  const int b = blockIdx.y;
  const int i0 = blockIdx.x * 32;
  const int t = threadIdx.x;
  const int w = t >> 6, lane = t & 63;
  const int rg = w >> 1, cg = w & 1;
  const int lr = lane & 15, hi = lane >> 4;
  const int fcol = 8 * hi;

  __shared__ __align__(16) bf16_t sA[2][32][40];
  __shared__ __align__(16) bf16_t sB[2][256][40];
  __shared__ __align__(16) bf16_t sK[32][264];
  __shared__ float sS[256], sT1[256], sR[256], sW1[256], sVS[256];
  __shared__ float sU[32];
  __shared__ float red[256];
  __shared__ float sdt_sh;

  const bf16_t* Ab  = (const bf16_t*)(ws + OFF_AB);
  const bf16_t* BmT = (const bf16_t*)(ws + OFF_BMT);
  const bf16_t* Gb  = (const bf16_t*)(ws + OFF_G) + (size_t)b * 65536;

  sS[t]  = ws[OFF_S + b * CCH + t];
  sT1[t] = ws[OFF_T1 + t];
  sR[t]  = ws[OFF_R + t];
  sW1[t] = ws[OFF_W1 + t];
  __syncthreads();
  red[t] = sS[t] * sT1[t];
  __syncthreads();
  for (int off = 128; off; off >>= 1) { if (t < off) red[t] += red[t + off]; __syncthreads(); }
  if (t == 0) sdt_sh = red[0];
  {
    float a = 0.f;
    for (int k8 = 0; k8 < 256; k8 += 8) {
      const bf16x8 v = *(const bf16x8*)&BmT[(size_t)t * CCH + k8];
#pragma unroll
      for (int q = 0; q < 8; ++q) a += (float)v[q] * sS[k8 + q];
    }
    sVS[t] = a;
  }
  if (t < 32) {
    float a = 0.f;
    for (int k8 = 0; k8 < 256; k8 += 8) {
      const bf16x8 v = *(const bf16x8*)&Ab[(size_t)(i0 + t) * CCH + k8];
#pragma unroll
      for (int q = 0; q < 8; ++q) a += (float)v[q] * sS[k8 + q];
    }
    sU[t] = a;
  }

  const f32x4 z4 = {0.f, 0.f, 0.f, 0.f};
  const int arow = t >> 2, achk = (t & 3) * 8;

  // ---- phase B: K = A @ G (G symmetric) ----
  f32x4 acc[8];
#pragma unroll
  for (int fc = 0; fc < 8; ++fc) acc[fc] = z4;
  bf16x8 ra;
  bf16x8 gb8[4];
  auto LOADB = [&](int k) {
    if (t < 128) ra = *(const bf16x8*)&Ab[(size_t)(i0 + arow) * CCH + k + achk];
#pragma unroll
    for (int h = 0; h < 4; ++h)
      gb8[h] = *(const bf16x8*)&Gb[(size_t)(64 * h + arow) * CCH + k + achk];
  };
  auto WRITEB = [&](int q) {
    if (t < 128) *(bf16x8*)&sA[q][arow][achk] = ra;
#pragma unroll
    for (int h = 0; h < 4; ++h)
      *(bf16x8*)&sB[q][64 * h + arow][achk] = gb8[h];
  };
  LOADB(0);
  WRITEB(0);
  __syncthreads();
  int cur = 0;
  for (int ks = 0; ks < 8; ++ks) {
    if (ks < 7) LOADB(32 * (ks + 1));
    const bf16x8 af = *(const bf16x8*)&sA[cur][16 * rg + lr][fcol];
#pragma unroll
    for (int fc = 0; fc < 8; ++fc) {
      const bf16x8 bv = *(const bf16x8*)&sB[cur][128 * cg + 16 * fc + lr][fcol];
      acc[fc] = __builtin_amdgcn_mfma_f32_16x16x32_bf16(af, bv, acc[fc], 0, 0, 0);
    }
    if (ks < 7) WRITEB(cur ^ 1);
    __syncthreads();
    cur ^= 1;
  }
  // K -> LDS bf16
#pragma unroll
  for (int fc = 0; fc < 8; ++fc)
#pragma unroll
    for (int reg = 0; reg < 4; ++reg)
      sK[16 * rg + 4 * hi + reg][128 * cg + 16 * fc + lr] = (bf16_t)acc[fc][reg];
  __syncthreads();

  // e (t<32)
  if (t < 32) {
    float dot = 0.f;
    for (int k8 = 0; k8 < 256; k8 += 8) {
      const bf16x8 v = *(const bf16x8*)&sK[t][k8];
#pragma unroll
      for (int q = 0; q < 8; ++q) dot += (float)v[q] * sT1[k8 + q];
    }
    const float c1 = ws[OFF_C1];
    const float ui = sU[t], w1i = sW1[i0 + t];
    ws[OFF_E + b * CCH + i0 + t] = INVN * (dot + c1 * ui + sdt_sh * w1i) + c1 * w1i + Wb[i0 + t];
  }

  // ---- phase C: Mcore = K @ Bm ----
  f32x4 acc2[8];
#pragma unroll
  for (int fc = 0; fc < 8; ++fc) acc2[fc] = z4;
  bf16x8 rb[4];
  auto LOADC = [&](int k) {
#pragma unroll
    for (int h = 0; h < 4; ++h)
      rb[h] = *(const bf16x8*)&BmT[(size_t)(64 * h + arow) * CCH + k + achk];
  };
  auto WRITEC = [&](int q) {
#pragma unroll
    for (int h = 0; h < 4; ++h)
      *(bf16x8*)&sB[q][64 * h + arow][achk] = rb[h];
  };
  LOADC(0);
  WRITEC(0);
  __syncthreads();
  cur = 0;
  for (int ks = 0; ks < 8; ++ks) {
    if (ks < 7) LOADC(32 * (ks + 1));
    const bf16x8 af = *(const bf16x8*)&sK[16 * rg + lr][32 * ks + fcol];
#pragma unroll
    for (int fc = 0; fc < 8; ++fc) {
      const bf16x8 bv = *(const bf16x8*)&sB[cur][128 * cg + 16 * fc + lr][fcol];
      acc2[fc] = __builtin_amdgcn_mfma_f32_16x16x32_bf16(af, bv, acc2[fc], 0, 0, 0);
    }
    if (ks < 7) WRITEC(cur ^ 1);
    __syncthreads();
    cur ^= 1;
  }

  // epilogue: M' = (acc2 + u r^T + w1 vs^T)/N + w1 r^T + I  (bf16), into sK
  bf16_t* Mp = (bf16_t*)(ws + OFF_MP) + (size_t)b * 65536;
#pragma unroll
  for (int fc = 0; fc < 8; ++fc) {
    const int j = 128 * cg + 16 * fc + lr;
    const float rj = sR[j], vsj = sVS[j];
#pragma unroll
    for (int reg = 0; reg < 4; ++reg) {
      const int il = 16 * rg + 4 * hi + reg;
      const float ui = sU[il], w1i = sW1[i0 + il];
      float m = (acc2[fc][reg] + ui * rj + w1i * vsj) * INVN + w1i * rj;
      if (i0 + il == j) m += 1.0f;
      sK[16 * rg + 4 * hi + reg][128 * cg + 16 * fc + lr] = (bf16_t)m;
    }
  }
  __syncthreads();
  // coalesced M' store via sK bounce (32 rows x 256 cols, 256 threads x 4 bf16x8)
  {
    const int row = t >> 3;            // 0..31
    const int c32 = (t & 7) * 32;
#pragma unroll
    for (int q = 0; q < 4; ++q) {
      const bf16x8 v = *(const bf16x8*)&sK[row][c32 + 8 * q];
      *(bf16x8*)&Mp[(size_t)(i0 + row) * CCH + c32 + 8 * q] = v;
    }
  }
}

// ---------- Z^T 64-n tiles via MFMA, dbuf. APPLY=0: BN partials; 1: write out ----------
template <int APPLY>
__global__ __launch_bounds__(256) void k_zmm(float* __restrict__ ws, float* __restrict__ out) {
  const int b = blockIdx.y, nblk = blockIdx.x;      // 64 nblks of 64
  const int n0 = nblk * 64;
  const int t = threadIdx.x;
  const int w = t >> 6, lane = t & 63;
  const int rg = w >> 1, cg = w & 1;
  __shared__ __align__(16) bf16_t sA[2][64][40];
  __shared__ __align__(16) bf16_t sB[2][256][40];
  __shared__ float sC1[256], sC2[256];
  __shared__ float redS[4][128], redQ[4][128];
  {
    const float e = ws[OFF_E + b * CCH + t];
    if (APPLY) {
      const float sc = ws[OFF_SCALE + t];
      sC1[t] = sc;
      sC2[t] = e * sc + ws[OFF_SHIFT + t];
    } else {
      sC1[t] = e;
    }
  }
  const bf16_t* Xit = (const bf16_t*)(ws + OFF_XIT) + (size_t)b * NPIX * CCH;
  const bf16_t* Mp = (const bf16_t*)(ws + OFF_MP) + (size_t)b * 65536;
  const f32x4 z4 = {0.f, 0.f, 0.f, 0.f};
  f32x4 acc[2][8];
#pragma unroll
  for (int fr = 0; fr < 2; ++fr)
#pragma unroll
    for (int fc = 0; fc < 8; ++fc) acc[fr][fc] = z4;
  const int arow = t >> 2, achk = (t & 3) * 8;
  bf16x8 ra, rb0, rb1, rb2, rb3;
  ra  = *(const bf16x8*)(Xit + (size_t)(n0 + arow) * CCH + achk);
  rb0 = *(const bf16x8*)(Mp + (size_t)(arow)       * CCH + achk);
  rb1 = *(const bf16x8*)(Mp + (size_t)(64 + arow)  * CCH + achk);
  rb2 = *(const bf16x8*)(Mp + (size_t)(128 + arow) * CCH + achk);
  rb3 = *(const bf16x8*)(Mp + (size_t)(192 + arow) * CCH + achk);
  *(bf16x8*)&sA[0][arow][achk] = ra;
  *(bf16x8*)&sB[0][arow][achk] = rb0;
  *(bf16x8*)&sB[0][64 + arow][achk] = rb1;
  *(bf16x8*)&sB[0][128 + arow][achk] = rb2;
  *(bf16x8*)&sB[0][192 + arow][achk] = rb3;
  __syncthreads();
  int cur = 0;
  for (int ks = 0; ks < 8; ++ks) {
    const int nk = 32 * (ks + 1);
    if (ks < 7) {
      ra  = *(const bf16x8*)(Xit + (size_t)(n0 + arow) * CCH + nk + achk);
      rb0 = *(const bf16x8*)(Mp + (size_t)(arow)       * CCH + nk + achk);
      rb1 = *(const bf16x8*)(Mp + (size_t)(64 + arow)  * CCH + nk + achk);
      rb2 = *(const bf16x8*)(Mp + (size_t)(128 + arow) * CCH + nk + achk);
      rb3 = *(const bf16x8*)(Mp + (size_t)(192 + arow) * CCH + nk + achk);
    }
    const int fcol = 8 * (lane >> 4);
    const int lr = lane & 15;
    const bf16x8 af0 = *(const bf16x8*)&sA[cur][32 * rg + lr][fcol];
    const bf16x8 af1 = *(const bf16x8*)&sA[cur][32 * rg + 16 + lr][fcol];
#pragma unroll
    for (int fc = 0; fc < 8; ++fc) {
      const bf16x8 bv = *(const bf16x8*)&sB[cur][128 * cg + 16 * fc + lr][fcol];
      acc[0][fc] = __builtin_amdgcn_mfma_f32_16x16x32_bf16(af0, bv, acc[0][fc], 0, 0, 0);
      acc[1][fc] = __builtin_amdgcn_mfma_f32_16x16x32_bf16(af1, bv, acc[1][fc], 0, 0, 0);
    }
    if (ks < 7) {
      *(bf16x8*)&sA[cur ^ 1][arow][achk] = ra;
      *(bf16x8*)&sB[cur ^ 1][arow][achk] = rb0;
      *(bf16x8*)&sB[cur ^ 1][64 + arow][achk] = rb1;
      *(bf16x8*)&sB[cur ^ 1][128 + arow][achk] = rb2;
      *(bf16x8*)&sB[cur ^ 1][192 + arow][achk] = rb3;
    }
    __syncthreads();
    cur ^= 1;
  }
  if (APPLY) {
#pragma unroll
    for (int fc = 0; fc < 8; ++fc) {
      const int c = 128 * cg + 16 * fc + (lane & 15);
      const float sc = sC1[c], b2 = sC2[c];
      float* op = out + ((size_t)b * CCH + c) * NPIX + n0 + 32 * rg + ((lane >> 4) << 2);
#pragma unroll
      for (int fr = 0; fr < 2; ++fr) {
        float4 v;
        v.x = acc[fr][fc][0] * sc + b2;
        v.y = acc[fr][fc][1] * sc + b2;
        v.z = acc[fr][fc][2] * sc + b2;
        v.w = acc[fr][fc][3] * sc + b2;
        *(float4*)(op + 16 * fr) = v;
      }
    }
  } else {
    float ps[8], pq[8];
#pragma unroll
    for (int fc = 0; fc < 8; ++fc) {
      const int c = 128 * cg + 16 * fc + (lane & 15);
      const float e = sC1[c];
      float s = 0.f, q = 0.f;
#pragma unroll
      for (int fr = 0; fr < 2; ++fr)
#pragma unroll
        for (int reg = 0; reg < 4; ++reg) {
          const float z = acc[fr][fc][reg] + e;
          s += z; q += z * z;
        }
      s += __shfl_xor(s, 16); s += __shfl_xor(s, 32);
      q += __shfl_xor(q, 16); q += __shfl_xor(q, 32);
      ps[fc] = s; pq[fc] = q;
    }
    if (lane < 16) {
#pragma unroll
      for (int fc = 0; fc < 8; ++fc) {
        redS[w][16 * fc + lane] = ps[fc];
        redQ[w][16 * fc + lane] = pq[fc];
      }
    }
    __syncthreads();
    if (t < 256) {
      const int cg2 = t >> 7, c = t & 127;
      float s = 0.f, q = 0.f;
#pragma unroll
      for (int rg2 = 0; rg2 < 2; ++rg2) {
        s += redS[rg2 * 2 + cg2][c];
        q += redQ[rg2 * 2 + cg2][c];
      }
      ws[OFF_ZPS + (size_t)t * 512 + b * 64 + nblk] = s;
      ws[OFF_ZPQ + (size_t)t * 512 + b * 64 + nblk] = q;
    }
  }
}

// ---------- BN stats -> scale/shift ----------
__global__ __launch_bounds__(64) void k_bnstats(const float* __restrict__ gamma,
                                                const float* __restrict__ beta,
                                                float* __restrict__ ws) {
  const int c = blockIdx.x, t = threadIdx.x;
  const float* PS = ws + OFF_ZPS + (size_t)c * 512;
  const float* PQ = ws + OFF_ZPQ + (size_t)c * 512;
  float s = 0.f, q = 0.f;
#pragma unroll
  for (int e = 0; e < 8; ++e) { s += PS[t + 64 * e]; q += PQ[t + 64 * e]; }
#pragma unroll
  for (int off = 32; off; off >>= 1) { s += __shfl_down(s, off); q += __shfl_down(q, off); }
  if (t == 0) {
    const float mean = s * INVCNT;
    const float var = q * INVCNT - mean * mean;
    const float sc = gamma[c] * rsqrtf(var + 1e-5f);
    ws[OFF_SCALE + c] = sc;
    ws[OFF_SHIFT + c] = beta[c] - mean * sc;
  }
}

extern "C" void kernel_launch(void* const* d_in, const int* in_sizes, int n_in,
                              void* d_out, int out_size, void* d_ws, size_t ws_size,
                              hipStream_t stream) {
  const float* xi  = (const float*)d_in[0];
  const float* xj  = (const float*)d_in[1];
  const float* gw  = (const float*)d_in[2];
  const float* gb  = (const float*)d_in[3];
  const float* thw = (const float*)d_in[4];
  const float* thb = (const float*)d_in[5];
  const float* phw = (const float*)d_in[6];
  const float* phb = (const float*)d_in[7];
  const float* Ww  = (const float*)d_in[8];
  const float* Wb  = (const float*)d_in[9];
  const float* gamma = (const float*)d_in[10];
  const float* beta  = (const float*)d_in[11];
  float* ws = (float*)d_ws;
  float* out = (float*)d_out;

  k_mega<<<dim3(177, 8), 512, 0, stream>>>(xi, xj, Ww, gw, phw, thw, gb, phb, thb, ws);
  k_greduce<<<dim3(32, 8), 256, 0, stream>>>(ws);
  k_kmmat<<<dim3(8, 8), 256, 0, stream>>>(Wb, ws);
  k_zmm<0><<<dim3(64, 8), 256, 0, stream>>>(ws, out);
  k_bnstats<<<256, 64, 0, stream>>>(gamma, beta, ws);
  k_zmm<1><<<dim3(64, 8), 256, 0, stream>>>(ws, out);
}